// Round 6
// baseline (525.077 us; speedup 1.0000x reference)
//
#include <hip/hip_runtime.h>

#define DIM 2048
#define NB 11
#define TPB 256
#define JPT 8               // j's per thread: TPB*JPT == DIM (one full row per block-iteration)
#define ROWS_PER_BLOCK 16

// ws layout: per j, 16 floats: slots [0..10] = chain scales in application
// order (s0 first), slot [11] = source index into x's last dim (int bits).
__global__ void monarch_prep(const float* __restrict__ blocks,
                             const int* __restrict__ perms,
                             float* __restrict__ ws) {
    int j = blockIdx.x * blockDim.x + threadIdx.x;
    if (j >= DIM) return;
    int k = j;
    float sc[NB];
    sc[NB - 1] = blocks[(NB - 1) * DIM + k];
    for (int i = NB - 2; i >= 0; --i) {
        k = perms[i * DIM + k];
        sc[i] = blocks[i * DIM + k];
    }
    float* o = ws + (size_t)j * 16;
    #pragma unroll
    for (int i = 0; i < NB; ++i) o[i] = sc[i];
    ((int*)o)[NB] = k;  // src index
}

// Apply the 11-multiply chain per element. Each block streams a contiguous
// ROWS_PER_BLOCK x 8KB region (pure sequential stream, m13 copy pattern).
__global__ __launch_bounds__(TPB, 4) void monarch_apply(const float* __restrict__ x,
                                                        const float* __restrict__ ws,
                                                        float* __restrict__ out,
                                                        int nrows) {
    const int j0 = threadIdx.x * JPT;  // 8 consecutive output columns

    // Scales into registers: 11 stages x 8 columns, static-indexed -> VGPRs.
    float sc[NB][JPT];
    int src[JPT];
    #pragma unroll
    for (int q = 0; q < JPT; ++q) {
        const float* w = ws + (size_t)(j0 + q) * 16;
        #pragma unroll
        for (int i = 0; i < NB; ++i) sc[i][q] = w[i];
        src[q] = ((const int*)w)[NB];
    }
    // Fast path: this thread's 8 sources are consecutive & 16B-aligned.
    bool consec = ((src[0] & 3) == 0);
    #pragma unroll
    for (int q = 1; q < JPT; ++q) consec = consec && (src[q] == src[0] + q);
    const int s0 = src[0];

    const int r0 = blockIdx.x * ROWS_PER_BLOCK;
    const int rend = min(ROWS_PER_BLOCK, nrows - r0);
    const float* xb = x + (size_t)r0 * DIM;
    float* ob = out + (size_t)r0 * DIM + j0;

#define MULCHAIN(v, q0)                                        \
    do {                                                       \
        _Pragma("unroll")                                      \
        for (int i = 0; i < NB; ++i) {                         \
            (v).x *= sc[i][(q0) + 0];                          \
            (v).y *= sc[i][(q0) + 1];                          \
            (v).z *= sc[i][(q0) + 2];                          \
            (v).w *= sc[i][(q0) + 3];                          \
        }                                                      \
    } while (0)

    if (consec) {
        int r = 0;
        // Unroll x2 rows: 4 independent float4 loads in flight per thread.
        for (; r + 1 < rend; r += 2) {
            const float* pa = xb + (size_t)r * DIM + s0;
            const float* pb = xb + (size_t)(r + 1) * DIM + s0;
            float4 a0 = *(const float4*)(pa);
            float4 a1 = *(const float4*)(pa + 4);
            float4 b0 = *(const float4*)(pb);
            float4 b1 = *(const float4*)(pb + 4);
            MULCHAIN(a0, 0); MULCHAIN(a1, 4);
            MULCHAIN(b0, 0); MULCHAIN(b1, 4);
            float* oa = ob + (size_t)r * DIM;
            float* obp = ob + (size_t)(r + 1) * DIM;
            *(float4*)(oa) = a0;
            *(float4*)(oa + 4) = a1;
            *(float4*)(obp) = b0;
            *(float4*)(obp + 4) = b1;
        }
        if (r < rend) {  // odd tail row
            const float* pa = xb + (size_t)r * DIM + s0;
            float4 a0 = *(const float4*)(pa);
            float4 a1 = *(const float4*)(pa + 4);
            MULCHAIN(a0, 0); MULCHAIN(a1, 4);
            float* oa = ob + (size_t)r * DIM;
            *(float4*)(oa) = a0;
            *(float4*)(oa + 4) = a1;
        }
    } else {
        // Generic gather path (not taken for identity permutations).
        for (int r = 0; r < rend; ++r) {
            const float* xr = xb + (size_t)r * DIM;
            float v[JPT];
            #pragma unroll
            for (int q = 0; q < JPT; ++q) v[q] = xr[src[q]];
            #pragma unroll
            for (int i = 0; i < NB; ++i)
                #pragma unroll
                for (int q = 0; q < JPT; ++q) v[q] *= sc[i][q];
            float* orow = ob + (size_t)r * DIM;
            #pragma unroll
            for (int q = 0; q < JPT; ++q) orow[q] = v[q];
        }
    }
#undef MULCHAIN
}

extern "C" void kernel_launch(void* const* d_in, const int* in_sizes, int n_in,
                              void* d_out, int out_size, void* d_ws, size_t ws_size,
                              hipStream_t stream) {
    const float* x      = (const float*)d_in[0];
    const float* blocks = (const float*)d_in[1];
    const int*   perms  = (const int*)d_in[2];
    float* out = (float*)d_out;
    float* ws  = (float*)d_ws;

    // Kernel 1: build per-j {11 chain scales, src index}. ws is re-poisoned
    // before every call, so this must run every launch (negligible: 8 blocks).
    monarch_prep<<<(DIM + TPB - 1) / TPB, TPB, 0, stream>>>(blocks, perms, ws);

    const int nrows = in_sizes[0] / DIM;  // 4*8192 = 32768
    const int grid = (nrows + ROWS_PER_BLOCK - 1) / ROWS_PER_BLOCK;  // 2048
    monarch_apply<<<grid, TPB, 0, stream>>>(x, ws, out, nrows);
}